// Round 6
// baseline (564.072 us; speedup 1.0000x reference)
//
#include <hip/hip_runtime.h>
#include <hip/hip_bf16.h>

typedef __bf16 bf16_t;
typedef __bf16 bf16x8 __attribute__((ext_vector_type(8)));
typedef __bf16 bf16x4 __attribute__((ext_vector_type(4)));
typedef float f32x4 __attribute__((ext_vector_type(4)));

#define B_DIM 4
#define NQ 2048
#define NK 2048
#define DMODEL 1024
#define NH 8
#define DHEAD 128

#define AS1 __attribute__((address_space(1)))
#define AS3 __attribute__((address_space(3)))

__device__ __forceinline__ void gl_lds16(const void* g, void* l) {
    __builtin_amdgcn_global_load_lds((const AS1 void*)g, (AS3 void*)l, 16, 0, 0);
}

// ---------------------------------------------------------------------------
// fp32 -> bf16 conversion, 6 pairs selected by blockIdx.y
// ---------------------------------------------------------------------------
struct CvtArgs {
    const float* s[6];
    bf16_t* d[6];
    int n[6];
};

__global__ __launch_bounds__(256) void cvt_k(CvtArgs a) {
    const int p = blockIdx.y;
    const float* s = a.s[p];
    bf16_t* d = a.d[p];
    const int n = a.n[p];
    const int stride = gridDim.x * 256 * 8;
    for (int i = (blockIdx.x * 256 + threadIdx.x) * 8; i < n; i += stride) {
        float4 x0 = *(const float4*)(s + i);
        float4 x1 = *(const float4*)(s + i + 4);
        bf16x8 o = {(bf16_t)x0.x, (bf16_t)x0.y, (bf16_t)x0.z, (bf16_t)x0.w,
                    (bf16_t)x1.x, (bf16_t)x1.y, (bf16_t)x1.z, (bf16_t)x1.w};
        *(bf16x8*)(d + i) = o;
    }
}

// ---------------------------------------------------------------------------
// GEMM core: A direct-to-register fragments; weights LDS double-buffered
// (2 x 8 KB), single barrier per K-step, prefetch issued post-barrier.
// C[M,N] = A[M,1024] * W[N,1024]^T + bias.
// MODE 0: bf16 out; MODE 1: fp32 = resid + relu(acc+bias); MODE 2: vT scatter
// ---------------------------------------------------------------------------
template <int MODE>
__device__ __forceinline__ void gemm_core(
    const bf16_t* A, const bf16_t* Bw, const float* bias, const float* resid,
    bf16_t* Cb, float* Cf, int N, int rowBase, int colBase, bf16_t (*sB)[4096])
{
    const int K = DMODEL;
    const int tid  = threadIdx.x;
    const int lane = tid & 63;
    const int wv   = tid >> 6;
    const int l16  = lane & 15;
    const int quad = (lane >> 4) & 3;
    const int kc4  = lane >> 4;
    const int wr   = wv >> 1, wc = wv & 1;

    const bf16_t* gB = Bw + (size_t)(colBase + wv * 32 + l16) * K + kc4 * 8;
    const bf16_t* gA = A + (size_t)(rowBase + wr * 64 + l16) * K + quad * 8;

    const f32x4 fz = {0.f, 0.f, 0.f, 0.f};
    f32x4 acc[4][4];
#pragma unroll
    for (int i = 0; i < 4; i++)
#pragma unroll
        for (int j = 0; j < 4; j++) acc[i][j] = fz;

    // prologue: stage W(0) into buf 0
    gl_lds16(gB,                  &sB[0][(wv * 2) * 512]);
    gl_lds16(gB + (size_t)16 * K, &sB[0][(wv * 2 + 1) * 512]);
    gB += 32;

    for (int t = 0; t < 32; t++) {
        __syncthreads();   // W(t) staged (issued one full compute phase ago)
        const int cur = t & 1;
        // A fragments for tile t: direct global->VGPR (issued BEFORE prefetch)
        bf16x8 aF[4];
#pragma unroll
        for (int mi = 0; mi < 4; mi++)
            aF[mi] = *(const bf16x8*)(gA + (size_t)mi * 16 * K + t * 32);
        // W(t+1) prefetch into the other buffer
        if (t + 1 < 32) {
            gl_lds16(gB,                  &sB[cur ^ 1][(wv * 2) * 512]);
            gl_lds16(gB + (size_t)16 * K, &sB[cur ^ 1][(wv * 2 + 1) * 512]);
            gB += 32;
        }
        bf16x8 bF[4];
#pragma unroll
        for (int ni = 0; ni < 4; ni++)
            bF[ni] = *(const bf16x8*)(&sB[cur][(wc * 4 + ni) * 512 + (quad * 16 + l16) * 8]);
#pragma unroll
        for (int mi = 0; mi < 4; mi++)
#pragma unroll
            for (int ni = 0; ni < 4; ni++)
                acc[mi][ni] = __builtin_amdgcn_mfma_f32_16x16x32_bf16(
                    aF[mi], bF[ni], acc[mi][ni], 0, 0, 0);
    }

#pragma unroll
    for (int mi = 0; mi < 4; mi++) {
#pragma unroll
        for (int ni = 0; ni < 4; ni++) {
            int row0 = rowBase + wr * 64 + mi * 16 + quad * 4;
            int col  = colBase + wc * 64 + ni * 16 + l16;
            float bvv = bias[col];
            if (MODE == 0) {
#pragma unroll
                for (int r = 0; r < 4; r++)
                    Cb[(size_t)(row0 + r) * N + col] = (bf16_t)(acc[mi][ni][r] + bvv);
            } else if (MODE == 1) {
#pragma unroll
                for (int r = 0; r < 4; r++) {
                    float v = acc[mi][ni][r] + bvv;
                    v = v > 0.f ? v : 0.f;
                    Cf[(size_t)(row0 + r) * N + col] =
                        resid[(size_t)(row0 + r) * N + col] + v;
                }
            } else {
                int b  = row0 >> 11;
                int n0 = row0 & 2047;
                int hh = col >> 7;
                int dd = col & 127;
                bf16x4 p = {(bf16_t)(acc[mi][ni][0] + bvv), (bf16_t)(acc[mi][ni][1] + bvv),
                            (bf16_t)(acc[mi][ni][2] + bvv), (bf16_t)(acc[mi][ni][3] + bvv)};
                *(bf16x4*)(Cb + (size_t)((b * NH + hh) * DHEAD + dd) * NK + n0) = p;
            }
        }
    }
}

// Fused Q/K/V projection (z = blockIdx.z)
__global__ __launch_bounds__(256) void proj_k(
    const bf16_t* Qc, const bf16_t* Kc,
    const bf16_t* Wqc, const bf16_t* Wkc, const bf16_t* Wvc,
    const float* bq, const float* bk, const float* bv,
    bf16_t* qbb, bf16_t* kbb, bf16_t* vT)
{
    __shared__ bf16_t sB[2][4096];
    const int z = blockIdx.z;
    const int rowBase = blockIdx.y * 128;
    const int colBase = blockIdx.x * 128;
    if (z == 0)
        gemm_core<0>(Qc, Wqc, bq, nullptr, qbb, nullptr, DMODEL, rowBase, colBase, sB);
    else if (z == 1)
        gemm_core<0>(Kc, Wkc, bk, nullptr, kbb, nullptr, DMODEL, rowBase, colBase, sB);
    else
        gemm_core<2>(Kc, Wvc, bv, nullptr, vT, nullptr, DMODEL, rowBase, colBase, sB);
}

// Wo GEMM: Cf = resid + relu(acc + bias)
__global__ __launch_bounds__(256) void gemm_wo(
    const bf16_t* __restrict__ A, const bf16_t* __restrict__ Bw,
    const float* __restrict__ bias, const float* resid, float* Cf)
{
    __shared__ bf16_t sB[2][4096];
    gemm_core<1>(A, Bw, bias, resid, nullptr, Cf, DMODEL,
                 blockIdx.y * 128, blockIdx.x * 128, sB);
}

// ---------------------------------------------------------------------------
// Transposed flash attention: S^T = K Q^T, O^T = V^T P^T.
// K LDS double-buffered (2 x 16 KB); V direct-to-register fragments issued
// before the K prefetch (FIFO vmcnt: PV's wait leaves prefetch in flight).
// One barrier per 64-key tile.  2 waves/block, 64 q-rows/block.
// ---------------------------------------------------------------------------
__global__ __launch_bounds__(128, 2) void attn_k(
    const bf16_t* __restrict__ qb, const bf16_t* __restrict__ kb,
    const bf16_t* __restrict__ vT, float* __restrict__ O)
{
    const int tid  = threadIdx.x;
    const int lane = tid & 63;
    const int wv   = tid >> 6;      // 0..1
    const int l16  = lane & 15;
    const int quad = (lane >> 4) & 3;
    const int bh   = blockIdx.x;    // bh-major: same bh -> same XCD
    const int b    = bh >> 3;
    const int h    = bh & 7;
    const int qt   = blockIdx.y * 64;
    const int qrow0 = b * NQ + qt + wv * 32;

    __shared__ bf16_t sK[2][8192];  // 2 x 16 frags of 1 KB

    bf16x8 qF[2][4];
#pragma unroll
    for (int qq = 0; qq < 2; qq++)
#pragma unroll
        for (int c = 0; c < 4; c++)
            qF[qq][c] = *(const bf16x8*)(qb + (size_t)(qrow0 + qq * 16 + l16) * DMODEL +
                                         h * DHEAD + c * 32 + quad * 8);

    const f32x4 fz = {0.f, 0.f, 0.f, 0.f};
    f32x4 accO[8][2];
#pragma unroll
    for (int db = 0; db < 8; db++)
#pragma unroll
        for (int qq = 0; qq < 2; qq++) accO[db][qq] = fz;
    float mq[2] = {-3e38f, -3e38f};
    float lq[2] = {0.f, 0.f};
    const float SC2 = 0.08838834764831845f * 1.44269504089f;  // log2(e)/sqrt(128)

    const bf16_t* gKb = kb + ((size_t)b * NK + l16) * DMODEL + h * DHEAD + quad * 8;
    const bf16_t* gVb = vT + ((size_t)bh * DHEAD + l16) * NK + quad * 8;
    const int qa   = (quad & 1) * 2;
    const int srcA = l16 + 16 * qa;
    const int srcB = srcA + 16;
    const bool hi  = (quad >> 1) != 0;

    // prologue: stage K(0) into buf 0 (wave wv covers kbi = 2wv, 2wv+1)
#pragma unroll
    for (int kb2 = 0; kb2 < 2; kb2++) {
        const int kbi = wv * 2 + kb2;
#pragma unroll
        for (int c = 0; c < 4; c++)
            gl_lds16(gKb + (size_t)(kbi * 16) * DMODEL + c * 32, &sK[0][(kbi * 4 + c) * 512]);
    }

    for (int it = 0; it < NK / 64; it++) {
        __syncthreads();   // K(it) staged (prefetch issued one compute phase ago)
        const int cur = it & 1;
        const int kt = it * 64;

        // V(it) fragments: direct global->VGPR, issued FIRST
        bf16x8 vF[8][2];
#pragma unroll
        for (int db = 0; db < 8; db++)
#pragma unroll
            for (int kc = 0; kc < 2; kc++)
                vF[db][kc] = *(const bf16x8*)(gVb + (size_t)(db * 16) * NK + kt + kc * 32);

        // K(it+1) prefetch into other buffer
        if (it + 1 < NK / 64) {
            const size_t ko = (size_t)(kt + 64);
#pragma unroll
            for (int kb2 = 0; kb2 < 2; kb2++) {
                const int kbi = wv * 2 + kb2;
#pragma unroll
                for (int c = 0; c < 4; c++)
                    gl_lds16(gKb + (ko + kbi * 16) * DMODEL + c * 32,
                             &sK[cur ^ 1][(kbi * 4 + c) * 512]);
            }
        }

        // ---- S^T = K Q^T
        f32x4 S[4][2];
#pragma unroll
        for (int kb4 = 0; kb4 < 4; kb4++) {
            S[kb4][0] = fz; S[kb4][1] = fz;
#pragma unroll
            for (int c = 0; c < 4; c++) {
                bf16x8 kF = *(const bf16x8*)(&sK[cur][(kb4 * 4 + c) * 512 + lane * 8]);
                S[kb4][0] = __builtin_amdgcn_mfma_f32_16x16x32_bf16(kF, qF[0][c], S[kb4][0], 0, 0, 0);
                S[kb4][1] = __builtin_amdgcn_mfma_f32_16x16x32_bf16(kF, qF[1][c], S[kb4][1], 0, 0, 0);
            }
        }

        // ---- online softmax (q = l16 per qq; keys spread over quads)
        float alph[2];
#pragma unroll
        for (int qq = 0; qq < 2; qq++) {
            float mx = fmaxf(fmaxf(fmaxf(S[0][qq][0], S[0][qq][1]), fmaxf(S[0][qq][2], S[0][qq][3])),
                       fmaxf(fmaxf(S[1][qq][0], S[1][qq][1]), fmaxf(S[1][qq][2], S[1][qq][3])));
            mx = fmaxf(mx, fmaxf(fmaxf(fmaxf(S[2][qq][0], S[2][qq][1]), fmaxf(S[2][qq][2], S[2][qq][3])),
                           fmaxf(fmaxf(S[3][qq][0], S[3][qq][1]), fmaxf(S[3][qq][2], S[3][qq][3]))));
            mx = fmaxf(mx, __shfl_xor(mx, 16));
            mx = fmaxf(mx, __shfl_xor(mx, 32));
            float mn = fmaxf(mq[qq], mx);
            float al = exp2f((mq[qq] - mn) * SC2);
            mq[qq] = mn;
            float mc = mn * SC2;
            float sum = 0.f;
#pragma unroll
            for (int kb4 = 0; kb4 < 4; kb4++)
#pragma unroll
                for (int r = 0; r < 4; r++) {
                    float p = exp2f(fmaf(S[kb4][qq][r], SC2, -mc));
                    S[kb4][qq][r] = p;
                    sum += p;
                }
            lq[qq] = lq[qq] * al + sum;
            alph[qq] = al;
        }
#pragma unroll
        for (int db = 0; db < 8; db++)
#pragma unroll
            for (int qq = 0; qq < 2; qq++)
#pragma unroll
                for (int r = 0; r < 4; r++) accO[db][qq][r] *= alph[qq];

        // ---- P: C-frags -> B-operand frags via shuffles
        uint2 pk[4][2];
#pragma unroll
        for (int kb4 = 0; kb4 < 4; kb4++)
#pragma unroll
            for (int qq = 0; qq < 2; qq++) {
                bf16x4 t = {(bf16_t)S[kb4][qq][0], (bf16_t)S[kb4][qq][1],
                            (bf16_t)S[kb4][qq][2], (bf16_t)S[kb4][qq][3]};
                pk[kb4][qq] = __builtin_bit_cast(uint2, t);
            }
        bf16x8 pF[2][2];
#pragma unroll
        for (int kc = 0; kc < 2; kc++)
#pragma unroll
            for (int qq = 0; qq < 2; qq++) {
                unsigned a0 = (unsigned)__shfl((int)pk[2 * kc][qq].x, srcA);
                unsigned b0 = (unsigned)__shfl((int)pk[2 * kc + 1][qq].x, srcA);
                unsigned a1 = (unsigned)__shfl((int)pk[2 * kc][qq].y, srcA);
                unsigned b1 = (unsigned)__shfl((int)pk[2 * kc + 1][qq].y, srcA);
                unsigned a2 = (unsigned)__shfl((int)pk[2 * kc][qq].x, srcB);
                unsigned b2 = (unsigned)__shfl((int)pk[2 * kc + 1][qq].x, srcB);
                unsigned a3 = (unsigned)__shfl((int)pk[2 * kc][qq].y, srcB);
                unsigned b3 = (unsigned)__shfl((int)pk[2 * kc + 1][qq].y, srcB);
                uint4 w = {hi ? b0 : a0, hi ? b1 : a1, hi ? b2 : a2, hi ? b3 : a3};
                pF[kc][qq] = __builtin_bit_cast(bf16x8, w);
            }

        // ---- O^T += V^T P^T (V from registers)
#pragma unroll
        for (int kc = 0; kc < 2; kc++)
#pragma unroll
            for (int db = 0; db < 8; db++) {
                accO[db][0] = __builtin_amdgcn_mfma_f32_16x16x32_bf16(vF[db][kc], pF[kc][0], accO[db][0], 0, 0, 0);
                accO[db][1] = __builtin_amdgcn_mfma_f32_16x16x32_bf16(vF[db][kc], pF[kc][1], accO[db][1], 0, 0, 0);
            }
    }

    // finalize denominators
    float inv[2];
#pragma unroll
    for (int qq = 0; qq < 2; qq++) {
        float s = lq[qq];
        s += __shfl_xor(s, 16);
        s += __shfl_xor(s, 32);
        inv[qq] = 1.0f / s;
    }

    // O = acc/l + q residual
#pragma unroll
    for (int qq = 0; qq < 2; qq++) {
        const int grow = qrow0 + qq * 16 + l16;
#pragma unroll
        for (int db = 0; db < 8; db++) {
            const int gcol = h * DHEAD + db * 16 + quad * 4;
            bf16x4 qr = *(const bf16x4*)(qb + (size_t)grow * DMODEL + gcol);
            f32x4 o;
#pragma unroll
            for (int r = 0; r < 4; r++)
                o[r] = accO[db][qq][r] * inv[qq] + (float)qr[r];
            *(f32x4*)(O + (size_t)grow * DMODEL + gcol) = o;
        }
    }
}

// ---------------------------------------------------------------------------
// LayerNorm over rows of 1024; optional extra bf16 output
// ---------------------------------------------------------------------------
__global__ __launch_bounds__(256) void ln_k(
    const float* __restrict__ X, const float* __restrict__ g,
    const float* __restrict__ bta, float* __restrict__ Yf, bf16_t* Yb)
{
    const int row = blockIdx.x;
    const int t = threadIdx.x;
    float4 x = *(const float4*)(X + (size_t)row * DMODEL + t * 4);
    float s  = x.x + x.y + x.z + x.w;
    float sq = x.x * x.x + x.y * x.y + x.z * x.z + x.w * x.w;
#pragma unroll
    for (int o = 1; o < 64; o <<= 1) {
        s  += __shfl_xor(s, o);
        sq += __shfl_xor(sq, o);
    }
    __shared__ float ls[8];
    int w = t >> 6, ln = t & 63;
    if (ln == 0) { ls[w] = s; ls[4 + w] = sq; }
    __syncthreads();
    s  = ls[0] + ls[1] + ls[2] + ls[3];
    sq = ls[4] + ls[5] + ls[6] + ls[7];
    float mu  = s * (1.f / DMODEL);
    float var = sq * (1.f / DMODEL) - mu * mu;
    float rs  = rsqrtf(var + 1e-5f);
    float4 gv = *(const float4*)(g + t * 4);
    float4 bv = *(const float4*)(bta + t * 4);
    float4 y;
    y.x = (x.x - mu) * rs * gv.x + bv.x;
    y.y = (x.y - mu) * rs * gv.y + bv.y;
    y.z = (x.z - mu) * rs * gv.z + bv.z;
    y.w = (x.w - mu) * rs * gv.w + bv.w;
    *(float4*)(Yf + (size_t)row * DMODEL + t * 4) = y;
    if (Yb) {
        bf16x4 yb = {(bf16_t)y.x, (bf16_t)y.y, (bf16_t)y.z, (bf16_t)y.w};
        *(bf16x4*)(Yb + (size_t)row * DMODEL + t * 4) = yb;
    }
}

// ---------------------------------------------------------------------------
extern "C" void kernel_launch(void* const* d_in, const int* in_sizes, int n_in,
                              void* d_out, int out_size, void* d_ws, size_t ws_size,
                              hipStream_t stream)
{
    const float* Q  = (const float*)d_in[0];
    const float* Kx = (const float*)d_in[1];
    const float* Wq = (const float*)d_in[2];
    const float* bq = (const float*)d_in[3];
    const float* Wk = (const float*)d_in[4];
    const float* bk = (const float*)d_in[5];
    const float* Wv = (const float*)d_in[6];
    const float* bv = (const float*)d_in[7];
    const float* Wo = (const float*)d_in[8];
    const float* bo = (const float*)d_in[9];
    const float* g0 = (const float*)d_in[10];
    const float* b0 = (const float*)d_in[11];
    const float* g1 = (const float*)d_in[12];
    const float* b1 = (const float*)d_in[13];
    float* out = (float*)d_out;

    char* ws = (char*)d_ws;
    bf16_t* Qc  = (bf16_t*)(ws);                  // 16,777,216
    bf16_t* Kc  = (bf16_t*)(ws + 16777216);       // 16,777,216
    bf16_t* Wqc = (bf16_t*)(ws + 33554432);       // 2,097,152
    bf16_t* Wkc = (bf16_t*)(ws + 35651584);
    bf16_t* Wvc = (bf16_t*)(ws + 37748736);
    bf16_t* Woc = (bf16_t*)(ws + 39845888);
    bf16_t* qbb = (bf16_t*)(ws + 41943040);       // 16,777,216
    bf16_t* kbb = (bf16_t*)(ws + 58720256);       // 16,777,216
    bf16_t* vT  = (bf16_t*)(ws + 75497472);       // 16,777,216
    float*  Obuf = (float*)(ws + 92274688);       // 33,554,432
    float*  Lf  = (float*)(ws);                   // alias Qc+Kc (dead after proj)
    bf16_t* Lb  = kbb;                            // alias kbb (dead after attn)

    CvtArgs ca;
    ca.s[0] = Q;  ca.d[0] = Qc;  ca.n[0] = B_DIM * NQ * DMODEL;
    ca.s[1] = Kx; ca.d[1] = Kc;  ca.n[1] = B_DIM * NK * DMODEL;
    ca.s[2] = Wq; ca.d[2] = Wqc; ca.n[2] = DMODEL * DMODEL;
    ca.s[3] = Wk; ca.d[3] = Wkc; ca.n[3] = DMODEL * DMODEL;
    ca.s[4] = Wv; ca.d[4] = Wvc; ca.n[4] = DMODEL * DMODEL;
    ca.s[5] = Wo; ca.d[5] = Woc; ca.n[5] = DMODEL * DMODEL;
    cvt_k<<<dim3(512, 6), 256, 0, stream>>>(ca);

    const int M = B_DIM * NQ;  // 8192

    proj_k<<<dim3(DMODEL / 128, M / 128, 3), 256, 0, stream>>>(
        Qc, Kc, Wqc, Wkc, Wvc, bq, bk, bv, qbb, kbb, vT);

    attn_k<<<dim3(B_DIM * NH, NQ / 64), 128, 0, stream>>>(qbb, kbb, vT, Obuf);

    ln_k<<<dim3(M), 256, 0, stream>>>(Obuf, g0, b0, Lf, Lb);

    gemm_wo<<<dim3(DMODEL / 128, M / 128), 256, 0, stream>>>(Lb, Woc, bo, Lf, Lf);

    ln_k<<<dim3(M), 256, 0, stream>>>(Lf, g1, b1, out, nullptr);
}